// Round 2
// baseline (414.834 us; speedup 1.0000x reference)
//
#include <hip/hip_runtime.h>
#include <hip/hip_bf16.h>
#include <cstdint>

// CAM (DANet channel attention): out = gamma * softmax(rowmax(E)-E) @ q + x,
// E = q q^T per batch, q = x reshaped [B, C, N], B=16 C=512 N=4096.
//
// R5 (resubmit after infra failure; source audited, no hang path found):
//  - pv: BK=32 double-buffered 2-phase loop with raw s_barrier + explicit
//    waitcnt (no __syncthreads full drain), and a 16B-granule XOR swizzle
//    (linear LDS dest + pre-swizzled GLOBAL source for global_load_lds,
//    swizzled ds_read address) -> conflict-free fragment reads.
//  - energy: same swizzle on its reg-staged tiles (ds_write and ds_read
//    both XOR'd) -> 8-way read conflict reduced to free 2-way.

typedef short    bf16x8 __attribute__((ext_vector_type(8)));
typedef float    f32x4  __attribute__((ext_vector_type(4)));
typedef uint16_t u16x4  __attribute__((ext_vector_type(4)));
typedef uint16_t u16x8  __attribute__((ext_vector_type(8)));

#define AS1 __attribute__((address_space(1)))
#define AS3 __attribute__((address_space(3)))

__device__ __forceinline__ void load_lds16(const void* g, void* l) {
  __builtin_amdgcn_global_load_lds((const AS1 unsigned int*)g,
                                   (AS3 unsigned int*)l, 16, 0, 0);
}

static constexpr int  BB  = 16, C = 512, N = 4096;
static constexpr long XSZ = (long)BB * C * N;   // 33,554,432 elems
static constexpr long ESZ = (long)BB * C * C;   //  4,194,304 elems
static constexpr int  ZSPLIT = 8;

// ---------------- 1. transpose hi(RNE) for PV: qT[b][n][c] ------------------
__global__ __launch_bounds__(256) void cam_splitT(
    const float* __restrict__ x, uint16_t* __restrict__ qT) {
  __shared__ uint16_t tile[64][68];  // 136B row stride: 8B-aligned rows
  const int t  = threadIdx.x;
  const int b  = blockIdx.z;
  const int c0 = blockIdx.y * 64;
  const int n0 = blockIdx.x * 64;
  const float* xb  = x  + (long)b * C * N;
  uint16_t*    qTb = qT + (long)b * N * C;
  const int cl = t >> 4;
  const int nl = (t & 15) * 4;
  for (int r = 0; r < 4; ++r) {
    const int  c   = cl + r * 16;
    const long off = (long)(c0 + c) * N + n0 + nl;
    const float4 v = *(const float4*)(xb + off);
    const float vv[4] = {v.x, v.y, v.z, v.w};
    u16x4 hv;
    for (int k = 0; k < 4; ++k) {
      __hip_bfloat16 hb = __float2bfloat16(vv[k]);  // RNE for PV precision
      hv[k] = *(uint16_t*)&hb;
    }
    *(u16x4*)&tile[c][nl] = hv;  // one ds_write_b64
  }
  __syncthreads();
  for (int r = 0; r < 4; ++r) {
    const int n  = cl + r * 16;
    const int cc = (t & 15) * 4;
    u16x4 o = {tile[cc + 0][n], tile[cc + 1][n], tile[cc + 2][n], tile[cc + 3][n]};
    *(u16x4*)(qTb + (long)(n0 + n) * C + c0 + cc) = o;
  }
}

// RTZ split of 4 fp32 into packed bf16 hi (2 u32) + compensation lo (2 u32).
__device__ __forceinline__ void split4(float4 v, uint2& h, uint2& l) {
  const uint32_t u0 = __float_as_uint(v.x), u1 = __float_as_uint(v.y);
  const uint32_t u2 = __float_as_uint(v.z), u3 = __float_as_uint(v.w);
  const float r0 = v.x - __uint_as_float(u0 & 0xffff0000u);
  const float r1 = v.y - __uint_as_float(u1 & 0xffff0000u);
  const float r2 = v.z - __uint_as_float(u2 & 0xffff0000u);
  const float r3 = v.w - __uint_as_float(u3 & 0xffff0000u);
  h.x = (u0 >> 16) | (u1 & 0xffff0000u);
  h.y = (u2 >> 16) | (u3 & 0xffff0000u);
  l.x = (__float_as_uint(r0) >> 16) | (__float_as_uint(r1) & 0xffff0000u);
  l.y = (__float_as_uint(r2) >> 16) | (__float_as_uint(r3) & 0xffff0000u);
}

// -- 2. energy = HH^T + HL^T + LH^T, triangle tiles, split-K=8, reg prefetch -
// LDS tiles are [128][32] bf16 (64B rows). Swizzle: 16B unit u at row r lives
// at u ^ ((r>>1)&3). Applied identically on ds_write (staging) and ds_read
// (fragments) -> conflict-free in both directions.
__global__ __launch_bounds__(256) void cam_energy(
    const float* __restrict__ x, float* __restrict__ E) {
  __shared__ uint16_t smem[4 * 128 * 32];  // Ahi | Alo | Bhi | Blo, 32 KB
  const int tid = threadIdx.x;
  const int wave = tid >> 6, lane = tid & 63;
  // XCD swizzle: 10 blocks of one (b,z) group share blockIdx % 8.
  const int idx = blockIdx.x;              // 0..1279
  const int low = idx & 7, chunk = idx >> 3;       // chunk 0..159
  const int gh = chunk / 10, t = chunk - gh * 10;  // gh 0..15, t 0..9
  const int g  = gh * 8 + low;             // 0..127 group = (b, z)
  const int b  = g >> 3, z = g & 7;
  const int ti = (t < 4) ? 0 : (t < 7) ? 1 : (t < 9) ? 2 : 3;
  const int tj = t - ((ti * (9 - ti)) >> 1) + ti;
  const bool diag = (ti == tj);
  const int i0 = ti * 128, j0 = tj * 128;
  const float* xb = x + (long)b * C * N;
  const int sr = tid >> 3;                 // staging row 0..31 (per pass)
  const int sc = (tid & 7) * 4;            // staging k-offset (bf16/f32 units)
  const float* pA = xb + (long)(i0 + sr) * N + sc;
  const float* pB = xb + (long)(j0 + sr) * N + sc;
  uint16_t* smAh = smem;
  uint16_t* smAl = smem + 4096;
  uint16_t* smBh = diag ? smem        : smem + 8192;
  uint16_t* smBl = diag ? smem + 4096 : smem + 12288;
  const int wr = wave >> 1, wc = wave & 1;
  const int m16 = lane & 15, q4 = lane >> 4;
  // swizzled 16B-unit for fragment reads (lane-constant: (r>>1)&3 == (m16>>1)&3)
  const int usw = (q4 ^ ((m16 >> 1) & 3)) * 8;
  f32x4 acc[4][4] = {};
  const int k0 = z * (N / ZSPLIT), kend = k0 + N / ZSPLIT;  // 512-wide chunk
  float4 ra[4], rb[4];
  #pragma unroll
  for (int p = 0; p < 4; ++p) {
    ra[p] = *(const float4*)(pA + k0 + (long)p * 32 * N);
    if (!diag) rb[p] = *(const float4*)(pB + k0 + (long)p * 32 * N);
  }
  for (int kk = k0; kk < kend; kk += 32) {
    #pragma unroll
    for (int p = 0; p < 4; ++p) {
      const int row = p * 32 + sr;
      const int scs = sc ^ (((row >> 1) & 3) << 3);  // 16B-granule XOR swizzle
      uint2 h, l;
      split4(ra[p], h, l);
      *(uint2*)(smAh + row * 32 + scs) = h;
      *(uint2*)(smAl + row * 32 + scs) = l;
      if (!diag) {
        split4(rb[p], h, l);
        *(uint2*)(smem + 8192  + row * 32 + scs) = h;
        *(uint2*)(smem + 12288 + row * 32 + scs) = l;
      }
    }
    __syncthreads();
    // prefetch next k-tile: VGPR loads stay in flight through the MFMAs
    const int kn = (kk + 32 < kend) ? kk + 32 : k0;  // clamp (values unused)
    #pragma unroll
    for (int p = 0; p < 4; ++p) {
      ra[p] = *(const float4*)(pA + kn + (long)p * 32 * N);
      if (!diag) rb[p] = *(const float4*)(pB + kn + (long)p * 32 * N);
    }
    bf16x8 ah[4], al[4], bh[4], bl[4];
    for (int i = 0; i < 4; ++i) {
      const int r = wr * 64 + i * 16 + m16;
      ah[i] = *(const bf16x8*)(smAh + r * 32 + usw);
      al[i] = *(const bf16x8*)(smAl + r * 32 + usw);
    }
    for (int j = 0; j < 4; ++j) {
      const int r = wc * 64 + j * 16 + m16;
      bh[j] = *(const bf16x8*)(smBh + r * 32 + usw);
      bl[j] = *(const bf16x8*)(smBl + r * 32 + usw);
    }
    for (int i = 0; i < 4; ++i)
      for (int j = 0; j < 4; ++j) {
        acc[i][j] = __builtin_amdgcn_mfma_f32_16x16x32_bf16(ah[i], bh[j], acc[i][j], 0, 0, 0);
        acc[i][j] = __builtin_amdgcn_mfma_f32_16x16x32_bf16(ah[i], bl[j], acc[i][j], 0, 0, 0);
        acc[i][j] = __builtin_amdgcn_mfma_f32_16x16x32_bf16(al[i], bh[j], acc[i][j], 0, 0, 0);
      }
    __syncthreads();
  }
  float* Eb = E + (long)z * ESZ + (long)b * C * C;
  for (int i = 0; i < 4; ++i) {
    const int rb_ = i0 + wr * 64 + i * 16 + q4 * 4;
    for (int j = 0; j < 4; ++j) {
      const int cc = j0 + wc * 64 + j * 16 + m16;
      for (int r = 0; r < 4; ++r)
        Eb[(long)(rb_ + r) * C + cc] = acc[i][j][r];
      if (!diag)  // mirror: E[cc][rb..rb+3] = acc[0..3], contiguous float4
        *(f32x4*)(Eb + (long)cc * C + rb_) = acc[i][j];
    }
  }
}

// ---------------- 3. softmax(max-E) == exp(rowmin-E)/sum, -> bf16 ----------
__global__ __launch_bounds__(256) void cam_softmax(
    const float* __restrict__ E, uint16_t* __restrict__ attn) {
  const int t = threadIdx.x;
  const int wave = t >> 6, lane = t & 63;
  const long row = (long)blockIdx.x * 4 + wave;   // 0..8191
  const float* e = E + row * C + lane * 8;
  float vv[8] = {};
  for (int z = 0; z < ZSPLIT; ++z) {
    const float4 a0 = *(const float4*)(e + (long)z * ESZ);
    const float4 a1 = *(const float4*)(e + (long)z * ESZ + 4);
    vv[0] += a0.x; vv[1] += a0.y; vv[2] += a0.z; vv[3] += a0.w;
    vv[4] += a1.x; vv[5] += a1.y; vv[6] += a1.z; vv[7] += a1.w;
  }
  float m = vv[0];
  for (int k = 1; k < 8; ++k) m = fminf(m, vv[k]);
  for (int s = 32; s; s >>= 1) m = fminf(m, __shfl_xor(m, s));
  float w[8], sum = 0.f;
  for (int k = 0; k < 8; ++k) { w[k] = __expf(m - vv[k]); sum += w[k]; }
  for (int s = 32; s; s >>= 1) sum += __shfl_xor(sum, s);
  const float inv = 1.0f / sum;
  u16x8 o;
  for (int k = 0; k < 8; ++k) {
    __hip_bfloat16 h = __float2bfloat16(w[k] * inv);
    o[k] = *(uint16_t*)&h;
  }
  *(u16x8*)(attn + row * C + lane * 8) = o;
}

// ---------------- 4. out = gamma * (attn @ q) + x ---------------------------
// BK=32, double-buffered (2 x 16KB = 32KB LDS -> still 5 blocks/CU).
// 2-phase pipeline: stage next tile BEFORE ds_read+MFMA; raw s_barrier with
// explicit waitcnt (no __syncthreads full-drain). Tiles are [128][32] bf16
// (64B rows) with the 16B-unit swizzle u ^= (row>>1)&3; global_load_lds
// writes linearly, so the swizzle is applied to the GLOBAL source address
// (rule: linear dest + inverse-swizzled source + swizzled read).
__global__ __launch_bounds__(256) void cam_pv(
    const uint16_t* __restrict__ attn, const uint16_t* __restrict__ qT,
    const float* __restrict__ x, const float* __restrict__ gamma,
    float* __restrict__ out) {
  __shared__ uint16_t smem[2 * 8192];   // [buf][A(8KB)|B(8KB)], 32 KB
  const int t = threadIdx.x;
  const int wave = t >> 6, lane = t & 63;
  const int b  = blockIdx.z;
  const int i0 = blockIdx.y * 128;
  const int n0 = blockIdx.x * 128;
  const uint16_t* Ab = attn + (long)b * C * C;
  const uint16_t* Tb = qT   + (long)b * N * C;
  const int wr = wave >> 1, wc = wave & 1;
  const int m16 = lane & 15, q4 = lane >> 4;
  // swizzled 16B-unit for fragment reads (lane-constant since rows step by 16)
  const int usw = (q4 ^ ((m16 >> 1) & 3)) * 8;
  f32x4 acc[4][4] = {};

  // stage one BK=32 tile pair (A 8KB + B 8KB) into buffer p: 4 loads/thread.
  // LDS dest is linear (li*16B); the swizzle permutes the global column.
  auto stage = [&](int p, int kk) {
    #pragma unroll
    for (int s = 0; s < 2; ++s) {
      const int li  = s * 256 + t;                        // 0..511
      const int row = li >> 2;                            // 0..127
      const int col = ((li & 3) ^ ((row >> 1) & 3)) * 8;  // swizzled src (u16)
      uint16_t* lp = smem + p * 8192 + li * 8;            // linear dest
      load_lds16(Ab + (long)(i0 + row) * C + kk + col, lp);
      load_lds16(Tb + (long)(n0 + row) * C + kk + col, lp + 4096);
    }
  };

  stage(0, 0);
  asm volatile("s_waitcnt vmcnt(0)" ::: "memory");
  __builtin_amdgcn_s_barrier();
  constexpr int NK = C / 32;            // 16
  for (int tk = 0; tk < NK; ++tk) {
    const int cur = tk & 1;
    if (tk + 1 < NK) stage(cur ^ 1, (tk + 1) * 32);  // issue next tile early
    const uint16_t* sa = smem + cur * 8192;
    bf16x8 a[4], bv[4];
    #pragma unroll
    for (int i = 0; i < 4; ++i)
      a[i]  = *(const bf16x8*)(sa +        (wr * 64 + i * 16 + m16) * 32 + usw);
    #pragma unroll
    for (int j = 0; j < 4; ++j)
      bv[j] = *(const bf16x8*)(sa + 4096 + (wc * 64 + j * 16 + m16) * 32 + usw);
    asm volatile("s_waitcnt lgkmcnt(0)" ::: "memory");  // fragments in regs
    __builtin_amdgcn_sched_barrier(0);
    #pragma unroll
    for (int i = 0; i < 4; ++i)
      #pragma unroll
      for (int j = 0; j < 4; ++j)
        acc[i][j] = __builtin_amdgcn_mfma_f32_16x16x32_bf16(a[i], bv[j], acc[i][j], 0, 0, 0);
    // next tile fully landed + everyone done reading cur -> safe to swap
    asm volatile("s_waitcnt vmcnt(0)" ::: "memory");
    __builtin_amdgcn_s_barrier();
  }
  const float g = gamma[0];
  const float* xb = x   + (long)b * C * N;
  float*       ob = out + (long)b * C * N;
  for (int i = 0; i < 4; ++i) {
    const int rb = i0 + wr * 64 + i * 16 + q4 * 4;
    for (int j = 0; j < 4; ++j) {
      const int cc = n0 + wc * 64 + j * 16 + m16;
      for (int r = 0; r < 4; ++r) {
        const long idx = (long)(rb + r) * N + cc;
        ob[idx] = g * acc[i][j][r] + xb[idx];
      }
    }
  }
}

extern "C" void kernel_launch(void* const* d_in, const int* in_sizes, int n_in,
                              void* d_out, int out_size, void* d_ws, size_t ws_size,
                              hipStream_t stream) {
  const float* x     = (const float*)d_in[0];
  const float* gamma = (const float*)d_in[1];
  float* out = (float*)d_out;
  char*  ws  = (char*)d_ws;
  // ws layout: qT 67MB | E partials 8x16.78MB=134MB | attn 8.4MB  (~210 MB)
  uint16_t* qT   = (uint16_t*)ws;
  float*    E    = (float*)  (ws + XSZ * 2);
  uint16_t* attn = (uint16_t*)(ws + XSZ * 2 + (long)ZSPLIT * ESZ * 4);

  cam_splitT <<<dim3(N / 64, C / 64, BB), 256, 0, stream>>>(x, qT);
  // 10 triangle tiles x 16 batches x 8 k-splits = 1280 blocks
  cam_energy <<<dim3(1280),               256, 0, stream>>>(x, E);
  cam_softmax<<<dim3((BB * C) / 4),       256, 0, stream>>>(E, attn);
  cam_pv     <<<dim3(N / 128, C / 128, BB), 256, 0, stream>>>(attn, qT, x, gamma, out);
}

// Round 3
// 414.475 us; speedup vs baseline: 1.0009x; 1.0009x over previous
//
#include <hip/hip_runtime.h>
#include <hip/hip_bf16.h>
#include <cstdint>

// CAM (DANet channel attention): out = gamma * softmax(rowmax(E)-E) @ q + x,
// E = q q^T per batch, q = x reshaped [B, C, N], B=16 C=512 N=4096.
//
// R6: latency-attack round (R5 showed conflicts=0 yet pv unchanged ->
// latency-bound, occupancy 2 blocks/CU):
//  - pv: 3-buffer BK=32 pipeline, counted s_waitcnt vmcnt(4) (never 0 in
//    steady state), ONE barrier per K-step. Stage tk+2 during compute of tk.
//  - splitT: LDS-free register 8x4 transpose (was: 4-way-conflicted scalar
//    ds_read_u16 gather).
//  - E partials re-laid out [b][row][z][col]: softmax reads one contiguous
//    16KB stream per row (was 8 streams at exactly 16 MiB stride -> HBM
//    channel aliasing suspect). Zero extra workspace.

typedef short    bf16x8 __attribute__((ext_vector_type(8)));
typedef float    f32x4  __attribute__((ext_vector_type(4)));
typedef uint16_t u16x4  __attribute__((ext_vector_type(4)));
typedef uint16_t u16x8  __attribute__((ext_vector_type(8)));

#define AS1 __attribute__((address_space(1)))
#define AS3 __attribute__((address_space(3)))

__device__ __forceinline__ void load_lds16(const void* g, void* l) {
  __builtin_amdgcn_global_load_lds((const AS1 unsigned int*)g,
                                   (AS3 unsigned int*)l, 16, 0, 0);
}

static constexpr int  BB  = 16, C = 512, N = 4096;
static constexpr long XSZ = (long)BB * C * N;   // 33,554,432 elems
static constexpr long ESZ = (long)BB * C * C;   //  4,194,304 elems
static constexpr int  ZSPLIT = 8;

// ---------------- 1. transpose hi(RNE) for PV: qT[b][n][c] ------------------
// Register transpose, no LDS. Lane owns an 8(c) x 4(n) block:
// 8 coalesced float4 reads (16-lane groups cover 256B runs), 4 u16x8 stores
// (4-lane groups cover 64B contiguous runs). Block tile: 128 c x 64 n.
__global__ __launch_bounds__(256) void cam_splitT(
    const float* __restrict__ x, uint16_t* __restrict__ qT) {
  const int t  = threadIdx.x;
  const int b  = blockIdx.z;
  const int c0 = blockIdx.y * 128;
  const int n0 = blockIdx.x * 64;
  const float* xb  = x  + (long)b * C * N;
  uint16_t*    qTb = qT + (long)b * N * C;
  const int ci = (t >> 4) * 8;        // 0..120
  const int nj = (t & 15) * 4;        // 0..60
  f32x4 v[8];
  #pragma unroll
  for (int i = 0; i < 8; ++i)
    v[i] = *(const f32x4*)(xb + (long)(c0 + ci + i) * N + n0 + nj);
  #pragma unroll
  for (int k = 0; k < 4; ++k) {
    u16x8 o;
    #pragma unroll
    for (int i = 0; i < 8; ++i) {
      __hip_bfloat16 hb = __float2bfloat16(v[i][k]);  // RNE for PV precision
      o[i] = *(uint16_t*)&hb;
    }
    *(u16x8*)(qTb + (long)(n0 + nj + k) * C + c0 + ci) = o;
  }
}

// RTZ split of 4 fp32 into packed bf16 hi (2 u32) + compensation lo (2 u32).
__device__ __forceinline__ void split4(float4 v, uint2& h, uint2& l) {
  const uint32_t u0 = __float_as_uint(v.x), u1 = __float_as_uint(v.y);
  const uint32_t u2 = __float_as_uint(v.z), u3 = __float_as_uint(v.w);
  const float r0 = v.x - __uint_as_float(u0 & 0xffff0000u);
  const float r1 = v.y - __uint_as_float(u1 & 0xffff0000u);
  const float r2 = v.z - __uint_as_float(u2 & 0xffff0000u);
  const float r3 = v.w - __uint_as_float(u3 & 0xffff0000u);
  h.x = (u0 >> 16) | (u1 & 0xffff0000u);
  h.y = (u2 >> 16) | (u3 & 0xffff0000u);
  l.x = (__float_as_uint(r0) >> 16) | (__float_as_uint(r1) & 0xffff0000u);
  l.y = (__float_as_uint(r2) >> 16) | (__float_as_uint(r3) & 0xffff0000u);
}

// -- 2. energy = HH^T + HL^T + LH^T, triangle tiles, split-K=8, reg prefetch -
// E partial layout: [b][row][z][col] -> row stride 8*C, z-slice offset z*C.
__global__ __launch_bounds__(256) void cam_energy(
    const float* __restrict__ x, float* __restrict__ E) {
  __shared__ uint16_t smem[4 * 128 * 32];  // Ahi | Alo | Bhi | Blo, 32 KB
  const int tid = threadIdx.x;
  const int wave = tid >> 6, lane = tid & 63;
  // XCD swizzle: 10 blocks of one (b,z) group share blockIdx % 8.
  const int idx = blockIdx.x;              // 0..1279
  const int low = idx & 7, chunk = idx >> 3;       // chunk 0..159
  const int gh = chunk / 10, t = chunk - gh * 10;  // gh 0..15, t 0..9
  const int g  = gh * 8 + low;             // 0..127 group = (b, z)
  const int b  = g >> 3, z = g & 7;
  const int ti = (t < 4) ? 0 : (t < 7) ? 1 : (t < 9) ? 2 : 3;
  const int tj = t - ((ti * (9 - ti)) >> 1) + ti;
  const bool diag = (ti == tj);
  const int i0 = ti * 128, j0 = tj * 128;
  const float* xb = x + (long)b * C * N;
  const int sr = tid >> 3;                 // staging row 0..31 (per pass)
  const int sc = (tid & 7) * 4;            // staging k-offset (bf16/f32 units)
  const float* pA = xb + (long)(i0 + sr) * N + sc;
  const float* pB = xb + (long)(j0 + sr) * N + sc;
  uint16_t* smAh = smem;
  uint16_t* smAl = smem + 4096;
  uint16_t* smBh = diag ? smem        : smem + 8192;
  uint16_t* smBl = diag ? smem + 4096 : smem + 12288;
  const int wr = wave >> 1, wc = wave & 1;
  const int m16 = lane & 15, q4 = lane >> 4;
  // swizzled 16B-unit for fragment reads (lane-constant: (r>>1)&3 == (m16>>1)&3)
  const int usw = (q4 ^ ((m16 >> 1) & 3)) * 8;
  f32x4 acc[4][4] = {};
  const int k0 = z * (N / ZSPLIT), kend = k0 + N / ZSPLIT;  // 512-wide chunk
  float4 ra[4], rb[4];
  #pragma unroll
  for (int p = 0; p < 4; ++p) {
    ra[p] = *(const float4*)(pA + k0 + (long)p * 32 * N);
    if (!diag) rb[p] = *(const float4*)(pB + k0 + (long)p * 32 * N);
  }
  for (int kk = k0; kk < kend; kk += 32) {
    #pragma unroll
    for (int p = 0; p < 4; ++p) {
      const int row = p * 32 + sr;
      const int scs = sc ^ (((row >> 1) & 3) << 3);  // 16B-granule XOR swizzle
      uint2 h, l;
      split4(ra[p], h, l);
      *(uint2*)(smAh + row * 32 + scs) = h;
      *(uint2*)(smAl + row * 32 + scs) = l;
      if (!diag) {
        split4(rb[p], h, l);
        *(uint2*)(smem + 8192  + row * 32 + scs) = h;
        *(uint2*)(smem + 12288 + row * 32 + scs) = l;
      }
    }
    __syncthreads();
    // prefetch next k-tile: VGPR loads stay in flight through the MFMAs
    const int kn = (kk + 32 < kend) ? kk + 32 : k0;  // clamp (values unused)
    #pragma unroll
    for (int p = 0; p < 4; ++p) {
      ra[p] = *(const float4*)(pA + kn + (long)p * 32 * N);
      if (!diag) rb[p] = *(const float4*)(pB + kn + (long)p * 32 * N);
    }
    bf16x8 ah[4], al[4], bh[4], bl[4];
    for (int i = 0; i < 4; ++i) {
      const int r = wr * 64 + i * 16 + m16;
      ah[i] = *(const bf16x8*)(smAh + r * 32 + usw);
      al[i] = *(const bf16x8*)(smAl + r * 32 + usw);
    }
    for (int j = 0; j < 4; ++j) {
      const int r = wc * 64 + j * 16 + m16;
      bh[j] = *(const bf16x8*)(smBh + r * 32 + usw);
      bl[j] = *(const bf16x8*)(smBl + r * 32 + usw);
    }
    for (int i = 0; i < 4; ++i)
      for (int j = 0; j < 4; ++j) {
        acc[i][j] = __builtin_amdgcn_mfma_f32_16x16x32_bf16(ah[i], bh[j], acc[i][j], 0, 0, 0);
        acc[i][j] = __builtin_amdgcn_mfma_f32_16x16x32_bf16(ah[i], bl[j], acc[i][j], 0, 0, 0);
        acc[i][j] = __builtin_amdgcn_mfma_f32_16x16x32_bf16(al[i], bh[j], acc[i][j], 0, 0, 0);
      }
    __syncthreads();
  }
  // E[b][row][z][col]: row stride 8C, this block's z-slice at +z*C.
  float* Eb = E + (long)b * C * C * 8 + (long)z * C;
  constexpr long RS = 8 * C;  // row stride in floats
  for (int i = 0; i < 4; ++i) {
    const int rb_ = i0 + wr * 64 + i * 16 + q4 * 4;
    for (int j = 0; j < 4; ++j) {
      const int cc = j0 + wc * 64 + j * 16 + m16;
      for (int r = 0; r < 4; ++r)
        Eb[(long)(rb_ + r) * RS + cc] = acc[i][j][r];
      if (!diag)  // mirror: E[cc][rb..rb+3] = acc[0..3], contiguous float4
        *(f32x4*)(Eb + (long)cc * RS + rb_) = acc[i][j];
    }
  }
}

// ---------------- 3. softmax(max-E) == exp(rowmin-E)/sum, -> bf16 ----------
// Reads are now one contiguous 16KB stream per row (z is second-minor dim).
__global__ __launch_bounds__(256) void cam_softmax(
    const float* __restrict__ E, uint16_t* __restrict__ attn) {
  const int t = threadIdx.x;
  const int wave = t >> 6, lane = t & 63;
  const long row = (long)blockIdx.x * 4 + wave;   // 0..8191
  const float* e = E + row * (8 * C) + lane * 8;
  float vv[8] = {};
  #pragma unroll
  for (int z = 0; z < ZSPLIT; ++z) {
    const f32x4 a0 = *(const f32x4*)(e + (long)z * C);
    const f32x4 a1 = *(const f32x4*)(e + (long)z * C + 4);
    vv[0] += a0[0]; vv[1] += a0[1]; vv[2] += a0[2]; vv[3] += a0[3];
    vv[4] += a1[0]; vv[5] += a1[1]; vv[6] += a1[2]; vv[7] += a1[3];
  }
  float m = vv[0];
  for (int k = 1; k < 8; ++k) m = fminf(m, vv[k]);
  for (int s = 32; s; s >>= 1) m = fminf(m, __shfl_xor(m, s));
  float w[8], sum = 0.f;
  for (int k = 0; k < 8; ++k) { w[k] = __expf(m - vv[k]); sum += w[k]; }
  for (int s = 32; s; s >>= 1) sum += __shfl_xor(sum, s);
  const float inv = 1.0f / sum;
  u16x8 o;
  for (int k = 0; k < 8; ++k) {
    __hip_bfloat16 h = __float2bfloat16(w[k] * inv);
    o[k] = *(uint16_t*)&h;
  }
  *(u16x8*)(attn + row * C + lane * 8) = o;
}

// ---------------- 4. out = gamma * (attn @ q) + x ---------------------------
// BK=32, TRIPLE-buffered (3 x 16KB = 48KB LDS -> 3 blocks/CU), counted-vmcnt
// pipeline: stage tk+2 while computing tk; wait vmcnt(4) (one stage still in
// flight) -> issue-to-wait distance ~2 iteration bodies covers load latency.
// One barrier per K-step. Swizzle as R5 (linear LDS dest, pre-swizzled global
// source, swizzled ds_read) -> conflict-free.
__global__ __launch_bounds__(256) void cam_pv(
    const uint16_t* __restrict__ attn, const uint16_t* __restrict__ qT,
    const float* __restrict__ x, const float* __restrict__ gamma,
    float* __restrict__ out) {
  __shared__ uint16_t smem[3 * 8192];   // 3 x [A(8KB)|B(8KB)] = 48 KB
  const int t = threadIdx.x;
  const int wave = t >> 6, lane = t & 63;
  const int b  = blockIdx.z;
  const int i0 = blockIdx.y * 128;
  const int n0 = blockIdx.x * 128;
  const uint16_t* Ab = attn + (long)b * C * C;
  const uint16_t* Tb = qT   + (long)b * N * C;
  const int wr = wave >> 1, wc = wave & 1;
  const int m16 = lane & 15, q4 = lane >> 4;
  // swizzled 16B-unit for fragment reads (lane-constant since rows step by 16)
  const int usw = (q4 ^ ((m16 >> 1) & 3)) * 8;
  f32x4 acc[4][4] = {};

  // stage one BK=32 tile pair (A 8KB + B 8KB) into buffer p: 4 loads/thread.
  // LDS dest is linear (li*16B); the swizzle permutes the global column.
  auto stage = [&](int p, int kk) {
    #pragma unroll
    for (int s = 0; s < 2; ++s) {
      const int li  = s * 256 + t;                        // 0..511
      const int row = li >> 2;                            // 0..127
      const int col = ((li & 3) ^ ((row >> 1) & 3)) * 8;  // swizzled src (u16)
      uint16_t* lp = smem + p * 8192 + li * 8;            // linear dest
      load_lds16(Ab + (long)(i0 + row) * C + kk + col, lp);
      load_lds16(Tb + (long)(n0 + row) * C + kk + col, lp + 4096);
    }
  };

  constexpr int NK = C / 32;            // 16
  stage(0, 0);
  stage(1, 32);                         // 8 loads outstanding
  for (int tk = 0; tk < NK; ++tk) {
    const int cur = tk % 3;
    // stage(tk) landed: allow stage(tk+1)'s 4 loads to remain in flight.
    if (tk == NK - 1) asm volatile("s_waitcnt vmcnt(0)" ::: "memory");
    else              asm volatile("s_waitcnt vmcnt(4)" ::: "memory");
    // all waves: buffer cur complete AND everyone done reading buf (tk-1)%3
    __builtin_amdgcn_s_barrier();
    if (tk + 2 < NK) stage((tk + 2) % 3, (tk + 2) * 32);
    const uint16_t* sa = smem + cur * 8192;
    bf16x8 a[4], bv[4];
    #pragma unroll
    for (int i = 0; i < 4; ++i)
      a[i]  = *(const bf16x8*)(sa +        (wr * 64 + i * 16 + m16) * 32 + usw);
    #pragma unroll
    for (int j = 0; j < 4; ++j)
      bv[j] = *(const bf16x8*)(sa + 4096 + (wc * 64 + j * 16 + m16) * 32 + usw);
    asm volatile("s_waitcnt lgkmcnt(0)" ::: "memory");  // fragments in regs
    __builtin_amdgcn_sched_barrier(0);
    #pragma unroll
    for (int i = 0; i < 4; ++i)
      #pragma unroll
      for (int j = 0; j < 4; ++j)
        acc[i][j] = __builtin_amdgcn_mfma_f32_16x16x32_bf16(a[i], bv[j], acc[i][j], 0, 0, 0);
  }
  const float g = gamma[0];
  const float* xb = x   + (long)b * C * N;
  float*       ob = out + (long)b * C * N;
  for (int i = 0; i < 4; ++i) {
    const int rb = i0 + wr * 64 + i * 16 + q4 * 4;
    for (int j = 0; j < 4; ++j) {
      const int cc = n0 + wc * 64 + j * 16 + m16;
      for (int r = 0; r < 4; ++r) {
        const long idx = (long)(rb + r) * N + cc;
        ob[idx] = g * acc[i][j][r] + xb[idx];
      }
    }
  }
}

extern "C" void kernel_launch(void* const* d_in, const int* in_sizes, int n_in,
                              void* d_out, int out_size, void* d_ws, size_t ws_size,
                              hipStream_t stream) {
  const float* x     = (const float*)d_in[0];
  const float* gamma = (const float*)d_in[1];
  float* out = (float*)d_out;
  char*  ws  = (char*)d_ws;
  // ws layout: qT 67MB | E partials [b][row][z][col] 134MB | attn 8.4MB
  uint16_t* qT   = (uint16_t*)ws;
  float*    E    = (float*)  (ws + XSZ * 2);
  uint16_t* attn = (uint16_t*)(ws + XSZ * 2 + (long)ZSPLIT * ESZ * 4);

  cam_splitT <<<dim3(N / 64, C / 128, BB), 256, 0, stream>>>(x, qT);
  // 10 triangle tiles x 16 batches x 8 k-splits = 1280 blocks
  cam_energy <<<dim3(1280),               256, 0, stream>>>(x, E);
  cam_softmax<<<dim3((BB * C) / 4),       256, 0, stream>>>(E, attn);
  cam_pv     <<<dim3(N / 128, C / 128, BB), 256, 0, stream>>>(attn, qT, x, gamma, out);
}